// Round 6
// baseline (259.884 us; speedup 1.0000x reference)
//
#include <hip/hip_runtime.h>
#include <math.h>

#define BB 8
#define SS 2048
#define NTOK (BB * SS)   // 16384
#define ATB_SPLIT 16

using bf16x8 = __attribute__((ext_vector_type(8))) short;
using f32x4  = __attribute__((ext_vector_type(4))) float;

__device__ __forceinline__ float gelu_exact(float v) {
    return 0.5f * v * (1.0f + erff(v * 0.70710678118654752f));
}
__device__ __forceinline__ unsigned short f2b(float f) {
    unsigned int u = __float_as_uint(f);
    u += 0x7FFFu + ((u >> 16) & 1u);
    return (unsigned short)(u >> 16);
}
__device__ __forceinline__ float b2f(unsigned short u) {
    return __uint_as_float((unsigned int)u << 16);
}
// load 8 fp32 from global, convert -> bf16x8 fragment
__device__ __forceinline__ bf16x8 ldg_f32_b8(const float* p) {
    float4 f0 = *(const float4*)p, f1 = *(const float4*)(p + 4);
    union { ushort4 u[2]; bf16x8 v; } r;
    r.u[0] = (ushort4){f2b(f0.x), f2b(f0.y), f2b(f0.z), f2b(f0.w)};
    r.u[1] = (ushort4){f2b(f1.x), f2b(f1.y), f2b(f1.z), f2b(f1.w)};
    return r.v;
}

// ---------------------------------------------------------------------------
// Fused window block: one block = one 64-token window (grid 256).
//   QKV (3 MFMA passes, W-frags direct from global bf16) -> causal attention
//   (scalar online softmax, Q slots overwritten in-place by attn out) ->
//   out-proj MFMA -> +x residual -> LN1 -> x1 fp32 + x1b bf16.
// ---------------------------------------------------------------------------
__global__ __launch_bounds__(256) void win_block(
    const float* __restrict__ x,
    const unsigned short* __restrict__ Wqkv,  // (384,128) bf16
    const float* __restrict__ b_in,
    const unsigned short* __restrict__ Wout,  // (128,128) bf16
    const float* __restrict__ b_out,
    const float* __restrict__ lng, const float* __restrict__ lnb,
    float* __restrict__ x1, unsigned short* __restrict__ x1b)
{
    __shared__ unsigned short Qs[64 * 136];   // q results; attn-out in-place
    __shared__ unsigned short KVs[64 * 256];  // [row][0..127]=k, [128..255]=v
    __shared__ float red[2][64][2];
    const int tid = threadIdx.x, m0 = blockIdx.x * 64;
    const int wv = tid >> 6, lane = tid & 63, ln = lane & 15, q = lane >> 4;
    const int wm = (wv >> 1) * 32, wn = (wv & 1) * 64;

    // A-fragments from x fp32, converted once (reused for all 3 passes)
    bf16x8 afr[4][2];
    #pragma unroll
    for (int kf = 0; kf < 4; ++kf)
        #pragma unroll
        for (int fm = 0; fm < 2; ++fm)
            afr[kf][fm] = ldg_f32_b8(x + (size_t)(m0 + wm + fm * 16 + ln) * 128 + kf * 32 + q * 8);

    #pragma unroll
    for (int p = 0; p < 3; ++p) {
        f32x4 acc[2][4] = {};
        #pragma unroll
        for (int kf = 0; kf < 4; ++kf) {
            bf16x8 b[4];
            #pragma unroll
            for (int fn = 0; fn < 4; ++fn)
                b[fn] = *(const bf16x8*)&Wqkv[(size_t)(p * 128 + wn + fn * 16 + ln) * 128 + kf * 32 + q * 8];
            #pragma unroll
            for (int fm = 0; fm < 2; ++fm)
                #pragma unroll
                for (int fn = 0; fn < 4; ++fn)
                    acc[fm][fn] = __builtin_amdgcn_mfma_f32_16x16x32_bf16(afr[kf][fm], b[fn], acc[fm][fn], 0, 0, 0);
        }
        #pragma unroll
        for (int fm = 0; fm < 2; ++fm)
            #pragma unroll
            for (int r = 0; r < 4; ++r) {
                int rl = wm + fm * 16 + q * 4 + r;
                #pragma unroll
                for (int fn = 0; fn < 4; ++fn) {
                    int col = wn + fn * 16 + ln;
                    unsigned short v = f2b(acc[fm][fn][r] + b_in[p * 128 + col]);
                    if (p == 0) Qs[rl * 136 + col] = v;
                    else        KVs[rl * 256 + (p - 1) * 128 + col] = v;
                }
            }
    }
    __syncthreads();

    // ---- causal attention: thread = (l = lane, wave = head-pair) ----
    {
        const int l = tid & 63, hp = tid >> 6;
        #pragma unroll
        for (int hh = 0; hh < 2; ++hh) {
            const int h = hp + hh * 4;
            float qr[16];
            {
                uint4 q0 = *(const uint4*)&Qs[l * 136 + h * 16];
                uint4 q1 = *(const uint4*)&Qs[l * 136 + h * 16 + 8];
                const unsigned short* p0 = (const unsigned short*)&q0;
                const unsigned short* p1 = (const unsigned short*)&q1;
                #pragma unroll
                for (int c = 0; c < 8; ++c) { qr[c] = b2f(p0[c]); qr[8 + c] = b2f(p1[c]); }
            }
            float m = -1e30f, ssum = 0.0f, o[16] = {};
            for (int j = 0; j <= l; ++j) {
                uint4 k0 = *(const uint4*)&KVs[j * 256 + h * 16];
                uint4 k1 = *(const uint4*)&KVs[j * 256 + h * 16 + 8];
                const unsigned short* kp0 = (const unsigned short*)&k0;
                const unsigned short* kp1 = (const unsigned short*)&k1;
                float s = 0.0f;
                #pragma unroll
                for (int c = 0; c < 8; ++c) {
                    s = fmaf(qr[c], b2f(kp0[c]), s);
                    s = fmaf(qr[8 + c], b2f(kp1[c]), s);
                }
                s *= 0.25f;
                float mnew = fmaxf(m, s);
                float corr = expf(m - mnew);
                float pp = expf(s - mnew);
                ssum = ssum * corr + pp;
                uint4 v0 = *(const uint4*)&KVs[j * 256 + 128 + h * 16];
                uint4 v1 = *(const uint4*)&KVs[j * 256 + 128 + h * 16 + 8];
                const unsigned short* vp0 = (const unsigned short*)&v0;
                const unsigned short* vp1 = (const unsigned short*)&v1;
                #pragma unroll
                for (int c = 0; c < 8; ++c) {
                    o[c]     = o[c]     * corr + pp * b2f(vp0[c]);
                    o[8 + c] = o[8 + c] * corr + pp * b2f(vp1[c]);
                }
                m = mnew;
            }
            float inv = 1.0f / ssum;
            ushort4 w0, w1, w2, w3;
            w0 = (ushort4){f2b(o[0]*inv),  f2b(o[1]*inv),  f2b(o[2]*inv),  f2b(o[3]*inv)};
            w1 = (ushort4){f2b(o[4]*inv),  f2b(o[5]*inv),  f2b(o[6]*inv),  f2b(o[7]*inv)};
            w2 = (ushort4){f2b(o[8]*inv),  f2b(o[9]*inv),  f2b(o[10]*inv), f2b(o[11]*inv)};
            w3 = (ushort4){f2b(o[12]*inv), f2b(o[13]*inv), f2b(o[14]*inv), f2b(o[15]*inv)};
            *(ushort4*)&Qs[l * 136 + h * 16]      = w0;
            *(ushort4*)&Qs[l * 136 + h * 16 + 4]  = w1;
            *(ushort4*)&Qs[l * 136 + h * 16 + 8]  = w2;
            *(ushort4*)&Qs[l * 136 + h * 16 + 12] = w3;
        }
    }
    __syncthreads();

    // ---- out-proj + residual(x) + LN1 ----
    f32x4 acc[2][4] = {};
    #pragma unroll
    for (int kf = 0; kf < 4; ++kf) {
        bf16x8 a[2], b[4];
        #pragma unroll
        for (int fm = 0; fm < 2; ++fm)
            a[fm] = *(const bf16x8*)&Qs[(wm + fm * 16 + ln) * 136 + kf * 32 + q * 8];
        #pragma unroll
        for (int fn = 0; fn < 4; ++fn)
            b[fn] = *(const bf16x8*)&Wout[(size_t)(wn + fn * 16 + ln) * 128 + kf * 32 + q * 8];
        #pragma unroll
        for (int fm = 0; fm < 2; ++fm)
            #pragma unroll
            for (int fn = 0; fn < 4; ++fn)
                acc[fm][fn] = __builtin_amdgcn_mfma_f32_16x16x32_bf16(a[fm], b[fn], acc[fm][fn], 0, 0, 0);
    }
    #pragma unroll
    for (int fm = 0; fm < 2; ++fm)
        #pragma unroll
        for (int r = 0; r < 4; ++r) {
            int rl = wm + fm * 16 + q * 4 + r;
            int row = m0 + rl;
            float s1 = 0.0f, s2 = 0.0f;
            #pragma unroll
            for (int fn = 0; fn < 4; ++fn) {
                int col = wn + fn * 16 + ln;
                float vv = acc[fm][fn][r] + b_out[col] + x[(size_t)row * 128 + col];
                acc[fm][fn][r] = vv;
                s1 += vv; s2 += vv * vv;
            }
            #pragma unroll
            for (int off = 1; off < 16; off <<= 1) {
                s1 += __shfl_xor(s1, off, 64);
                s2 += __shfl_xor(s2, off, 64);
            }
            if (ln == 0) { red[0][rl][wv & 1] = s1; red[1][rl][wv & 1] = s2; }
        }
    __syncthreads();
    #pragma unroll
    for (int fm = 0; fm < 2; ++fm)
        #pragma unroll
        for (int r = 0; r < 4; ++r) {
            int rl = wm + fm * 16 + q * 4 + r;
            int row = m0 + rl;
            float mu = (red[0][rl][0] + red[0][rl][1]) * (1.0f / 128.0f);
            float var = (red[1][rl][0] + red[1][rl][1]) * (1.0f / 128.0f) - mu * mu;
            float rs = rsqrtf(var + 1e-5f);
            #pragma unroll
            for (int fn = 0; fn < 4; ++fn) {
                int col = wn + fn * 16 + ln;
                float o = (acc[fm][fn][r] - mu) * rs * lng[col] + lnb[col];
                x1[(size_t)row * 128 + col] = o;
                x1b[(size_t)row * 128 + col] = f2b(o);
            }
        }
}

// ---------------------------------------------------------------------------
// Fused interaction block: one block = 8 s-values x all 8 batches (64 rows).
//   intQKV (q from seb, k/v from teb) -> len-8 MHA -> out-proj*sim + x2 -> out
// ---------------------------------------------------------------------------
__global__ __launch_bounds__(256) void inter_block(
    const unsigned short* __restrict__ seb, const unsigned short* __restrict__ teb,
    const unsigned short* __restrict__ Wint,  // (384,128) bf16
    const float* __restrict__ b_int,
    const unsigned short* __restrict__ Wio,   // (128,128) bf16
    const float* __restrict__ b_io,
    const float* __restrict__ sim, const float* __restrict__ x2,
    float* __restrict__ out)
{
    __shared__ unsigned short Qs[64 * 136];
    __shared__ unsigned short KVs[64 * 256];
    const int tid = threadIdx.x, s0 = blockIdx.x * 8;
    const int wv = tid >> 6, lane = tid & 63, ln = lane & 15, q = lane >> 4;
    const int wm = (wv >> 1) * 32, wn = (wv & 1) * 64;
    // rl = i*8+ss  ->  global row = i*2048 + s0 + ss

    bf16x8 afr[4][2];
    #pragma unroll
    for (int kf = 0; kf < 4; ++kf)
        #pragma unroll
        for (int fm = 0; fm < 2; ++fm) {
            int rl = wm + fm * 16 + ln;
            size_t g = (size_t)(rl >> 3) * 2048 + s0 + (rl & 7);
            afr[kf][fm] = *(const bf16x8*)&seb[g * 128 + kf * 32 + q * 8];
        }

    #pragma unroll
    for (int p = 0; p < 3; ++p) {
        if (p == 1) {   // switch A source to teb for k and v passes
            #pragma unroll
            for (int kf = 0; kf < 4; ++kf)
                #pragma unroll
                for (int fm = 0; fm < 2; ++fm) {
                    int rl = wm + fm * 16 + ln;
                    size_t g = (size_t)(rl >> 3) * 2048 + s0 + (rl & 7);
                    afr[kf][fm] = *(const bf16x8*)&teb[g * 128 + kf * 32 + q * 8];
                }
        }
        f32x4 acc[2][4] = {};
        #pragma unroll
        for (int kf = 0; kf < 4; ++kf) {
            bf16x8 b[4];
            #pragma unroll
            for (int fn = 0; fn < 4; ++fn)
                b[fn] = *(const bf16x8*)&Wint[(size_t)(p * 128 + wn + fn * 16 + ln) * 128 + kf * 32 + q * 8];
            #pragma unroll
            for (int fm = 0; fm < 2; ++fm)
                #pragma unroll
                for (int fn = 0; fn < 4; ++fn)
                    acc[fm][fn] = __builtin_amdgcn_mfma_f32_16x16x32_bf16(afr[kf][fm], b[fn], acc[fm][fn], 0, 0, 0);
        }
        #pragma unroll
        for (int fm = 0; fm < 2; ++fm)
            #pragma unroll
            for (int r = 0; r < 4; ++r) {
                int rl = wm + fm * 16 + q * 4 + r;
                #pragma unroll
                for (int fn = 0; fn < 4; ++fn) {
                    int col = wn + fn * 16 + ln;
                    unsigned short v = f2b(acc[fm][fn][r] + b_int[p * 128 + col]);
                    if (p == 0) Qs[rl * 136 + col] = v;
                    else        KVs[rl * 256 + (p - 1) * 128 + col] = v;
                }
            }
        __syncthreads();
    }

    // ---- len-8 attention: 512 tasks (ss,h,i), 2 per thread ----
    #pragma unroll
    for (int tt = 0; tt < 2; ++tt) {
        int task = tid + tt * 256;
        int ss = task >> 6, h = (task >> 3) & 7, i = task & 7;
        int rq = i * 8 + ss;
        float qr[16];
        {
            uint4 q0 = *(const uint4*)&Qs[rq * 136 + h * 16];
            uint4 q1 = *(const uint4*)&Qs[rq * 136 + h * 16 + 8];
            const unsigned short* p0 = (const unsigned short*)&q0;
            const unsigned short* p1 = (const unsigned short*)&q1;
            #pragma unroll
            for (int c = 0; c < 8; ++c) { qr[c] = b2f(p0[c]); qr[8 + c] = b2f(p1[c]); }
        }
        float sc[8];
        #pragma unroll
        for (int j = 0; j < 8; ++j) {
            uint4 k0 = *(const uint4*)&KVs[(j * 8 + ss) * 256 + h * 16];
            uint4 k1 = *(const uint4*)&KVs[(j * 8 + ss) * 256 + h * 16 + 8];
            const unsigned short* kp0 = (const unsigned short*)&k0;
            const unsigned short* kp1 = (const unsigned short*)&k1;
            float s = 0.0f;
            #pragma unroll
            for (int c = 0; c < 8; ++c) {
                s = fmaf(qr[c], b2f(kp0[c]), s);
                s = fmaf(qr[8 + c], b2f(kp1[c]), s);
            }
            sc[j] = s * 0.25f;
        }
        float mx = -1e30f;
        #pragma unroll
        for (int j = 0; j < 8; ++j) mx = fmaxf(mx, sc[j]);
        float pe[8], se = 0.0f;
        #pragma unroll
        for (int j = 0; j < 8; ++j) { pe[j] = expf(sc[j] - mx); se += pe[j]; }
        float inv = 1.0f / se;
        float o[16] = {};
        #pragma unroll
        for (int j = 0; j < 8; ++j) {
            uint4 v0 = *(const uint4*)&KVs[(j * 8 + ss) * 256 + 128 + h * 16];
            uint4 v1 = *(const uint4*)&KVs[(j * 8 + ss) * 256 + 128 + h * 16 + 8];
            const unsigned short* vp0 = (const unsigned short*)&v0;
            const unsigned short* vp1 = (const unsigned short*)&v1;
            #pragma unroll
            for (int c = 0; c < 8; ++c) {
                o[c]     += pe[j] * b2f(vp0[c]);
                o[8 + c] += pe[j] * b2f(vp1[c]);
            }
        }
        ushort4 w0 = (ushort4){f2b(o[0]*inv),  f2b(o[1]*inv),  f2b(o[2]*inv),  f2b(o[3]*inv)};
        ushort4 w1 = (ushort4){f2b(o[4]*inv),  f2b(o[5]*inv),  f2b(o[6]*inv),  f2b(o[7]*inv)};
        ushort4 w2 = (ushort4){f2b(o[8]*inv),  f2b(o[9]*inv),  f2b(o[10]*inv), f2b(o[11]*inv)};
        ushort4 w3 = (ushort4){f2b(o[12]*inv), f2b(o[13]*inv), f2b(o[14]*inv), f2b(o[15]*inv)};
        *(ushort4*)&Qs[rq * 136 + h * 16]      = w0;
        *(ushort4*)&Qs[rq * 136 + h * 16 + 4]  = w1;
        *(ushort4*)&Qs[rq * 136 + h * 16 + 8]  = w2;
        *(ushort4*)&Qs[rq * 136 + h * 16 + 12] = w3;
    }
    __syncthreads();

    // ---- out-proj * sim + x2 ----
    f32x4 acc[2][4] = {};
    #pragma unroll
    for (int kf = 0; kf < 4; ++kf) {
        bf16x8 a[2], b[4];
        #pragma unroll
        for (int fm = 0; fm < 2; ++fm)
            a[fm] = *(const bf16x8*)&Qs[(wm + fm * 16 + ln) * 136 + kf * 32 + q * 8];
        #pragma unroll
        for (int fn = 0; fn < 4; ++fn)
            b[fn] = *(const bf16x8*)&Wio[(size_t)(wn + fn * 16 + ln) * 128 + kf * 32 + q * 8];
        #pragma unroll
        for (int fm = 0; fm < 2; ++fm)
            #pragma unroll
            for (int fn = 0; fn < 4; ++fn)
                acc[fm][fn] = __builtin_amdgcn_mfma_f32_16x16x32_bf16(a[fm], b[fn], acc[fm][fn], 0, 0, 0);
    }
    #pragma unroll
    for (int fm = 0; fm < 2; ++fm)
        #pragma unroll
        for (int r = 0; r < 4; ++r) {
            int rl = wm + fm * 16 + q * 4 + r;
            size_t g = (size_t)(rl >> 3) * 2048 + s0 + (rl & 7);
            float sc = sim[g];
            #pragma unroll
            for (int fn = 0; fn < 4; ++fn) {
                int col = wn + fn * 16 + ln;
                out[g * 128 + col] = (acc[fm][fn][r] + b_io[col]) * sc + x2[g * 128 + col];
            }
        }
}

// ---------------------------------------------------------------------------
// Fused FFN: x2 = LN2( gelu(x1@w1^T+b1) @ w2^T + b2 + x1 ). 64-token blocks,
// grid 256. W-frags direct from global bf16; only Xs + Hs in LDS.
// ---------------------------------------------------------------------------
__global__ __launch_bounds__(256) void ffn_fused(
    const unsigned short* __restrict__ x1b, const float* __restrict__ x1,
    const unsigned short* __restrict__ w1, const unsigned short* __restrict__ w2,
    const float* __restrict__ b1, const float* __restrict__ b2,
    const float* __restrict__ lng, const float* __restrict__ lnb,
    float* __restrict__ x2)
{
    __shared__ unsigned short Xs[64 * 136];
    __shared__ unsigned short Hs[64 * 72];
    __shared__ float red[2][64][2];
    const int tid = threadIdx.x, t0 = blockIdx.x * 64;
    const int wv = tid >> 6, lane = tid & 63, ln = lane & 15, q = lane >> 4;
    const int wm = (wv >> 1) * 32;
    const int wn1 = (wv & 1) * 32, wn2 = (wv & 1) * 64;

    const uint4* X4 = (const uint4*)(x1b + (size_t)t0 * 128);
    #pragma unroll
    for (int t = 0; t < 4; ++t) {
        int idx = tid + t * 256;
        int r = idx >> 4, c = idx & 15;
        *(uint4*)&Xs[r * 136 + c * 8] = X4[r * 16 + c];
    }
    __syncthreads();

    bf16x8 xfr[4][2];
    #pragma unroll
    for (int kf = 0; kf < 4; ++kf)
        #pragma unroll
        for (int fm = 0; fm < 2; ++fm)
            xfr[kf][fm] = *(const bf16x8*)&Xs[(wm + fm * 16 + ln) * 136 + kf * 32 + q * 8];

    f32x4 acc2[2][4] = {};
    for (int ch = 0; ch < 8; ++ch) {
        const int hc0 = ch * 64;
        f32x4 acc1[2][2] = {};
        #pragma unroll
        for (int kf = 0; kf < 4; ++kf) {
            bf16x8 b[2];
            #pragma unroll
            for (int fn = 0; fn < 2; ++fn)
                b[fn] = *(const bf16x8*)&w1[(size_t)(hc0 + wn1 + fn * 16 + ln) * 128 + kf * 32 + q * 8];
            #pragma unroll
            for (int fm = 0; fm < 2; ++fm)
                #pragma unroll
                for (int fn = 0; fn < 2; ++fn)
                    acc1[fm][fn] = __builtin_amdgcn_mfma_f32_16x16x32_bf16(xfr[kf][fm], b[fn], acc1[fm][fn], 0, 0, 0);
        }
        #pragma unroll
        for (int fm = 0; fm < 2; ++fm)
            #pragma unroll
            for (int fn = 0; fn < 2; ++fn)
                #pragma unroll
                for (int r = 0; r < 4; ++r) {
                    int rl = wm + fm * 16 + q * 4 + r;
                    int col = wn1 + fn * 16 + ln;
                    Hs[rl * 72 + col] = f2b(gelu_exact(acc1[fm][fn][r] + b1[hc0 + col]));
                }
        __syncthreads();
        #pragma unroll
        for (int kf = 0; kf < 2; ++kf) {
            bf16x8 a[2], b[4];
            #pragma unroll
            for (int fm = 0; fm < 2; ++fm)
                a[fm] = *(const bf16x8*)&Hs[(wm + fm * 16 + ln) * 72 + kf * 32 + q * 8];
            #pragma unroll
            for (int fn = 0; fn < 4; ++fn)
                b[fn] = *(const bf16x8*)&w2[(size_t)(wn2 + fn * 16 + ln) * 512 + hc0 + kf * 32 + q * 8];
            #pragma unroll
            for (int fm = 0; fm < 2; ++fm)
                #pragma unroll
                for (int fn = 0; fn < 4; ++fn)
                    acc2[fm][fn] = __builtin_amdgcn_mfma_f32_16x16x32_bf16(a[fm], b[fn], acc2[fm][fn], 0, 0, 0);
        }
        __syncthreads();
    }
    #pragma unroll
    for (int fm = 0; fm < 2; ++fm)
        #pragma unroll
        for (int r = 0; r < 4; ++r) {
            int rl = wm + fm * 16 + q * 4 + r;
            int row = t0 + rl;
            float s1 = 0.0f, s2 = 0.0f;
            #pragma unroll
            for (int fn = 0; fn < 4; ++fn) {
                int col = wn2 + fn * 16 + ln;
                float vv = acc2[fm][fn][r] + b2[col] + x1[(size_t)row * 128 + col];
                acc2[fm][fn][r] = vv;
                s1 += vv; s2 += vv * vv;
            }
            #pragma unroll
            for (int off = 1; off < 16; off <<= 1) {
                s1 += __shfl_xor(s1, off, 64);
                s2 += __shfl_xor(s2, off, 64);
            }
            if (ln == 0) { red[0][rl][wv & 1] = s1; red[1][rl][wv & 1] = s2; }
        }
    __syncthreads();
    #pragma unroll
    for (int fm = 0; fm < 2; ++fm)
        #pragma unroll
        for (int r = 0; r < 4; ++r) {
            int rl = wm + fm * 16 + q * 4 + r;
            int row = t0 + rl;
            float mu = (red[0][rl][0] + red[0][rl][1]) * (1.0f / 128.0f);
            float var = (red[1][rl][0] + red[1][rl][1]) * (1.0f / 128.0f) - mu * mu;
            float rs = rsqrtf(var + 1e-5f);
            #pragma unroll
            for (int fn = 0; fn < 4; ++fn) {
                int col = wn2 + fn * 16 + ln;
                x2[(size_t)row * 128 + col] = (acc2[fm][fn][r] - mu) * rs * lng[col] + lnb[col];
            }
        }
}

// ---------------------------------------------------------------------------
// se/te projection + cosine norm, grid (256,2); A from fp32 global, W-frags
// from global bf16. No LDS staging.
// ---------------------------------------------------------------------------
__global__ __launch_bounds__(256) void stproj_kernel(
    const float* __restrict__ sp, const float* __restrict__ tp,
    const unsigned short* __restrict__ Wsp, const unsigned short* __restrict__ Wtp,
    const float* __restrict__ bsp, const float* __restrict__ btp,
    float* __restrict__ sn, float* __restrict__ tn,
    unsigned short* __restrict__ snb,
    unsigned short* __restrict__ seb, unsigned short* __restrict__ teb)
{
    __shared__ float red[64][2];
    const int tid = threadIdx.x, m0 = blockIdx.x * 64, y = blockIdx.y;
    const float* Af = y ? tp : sp;
    const unsigned short* W = y ? Wtp : Wsp;
    const float* bias = y ? btp : bsp;
    float* nrm = y ? tn : sn;
    unsigned short* nb = y ? nullptr : snb;
    unsigned short* raw = y ? teb : seb;
    const int wv = tid >> 6, lane = tid & 63, ln = lane & 15, q = lane >> 4;
    const int wm = (wv >> 1) * 32, wn = (wv & 1) * 64;

    f32x4 acc[2][4] = {};
    #pragma unroll
    for (int kf = 0; kf < 4; ++kf) {
        bf16x8 a[2], b[4];
        #pragma unroll
        for (int fm = 0; fm < 2; ++fm)
            a[fm] = ldg_f32_b8(Af + (size_t)(m0 + wm + fm * 16 + ln) * 128 + kf * 32 + q * 8);
        #pragma unroll
        for (int fn = 0; fn < 4; ++fn)
            b[fn] = *(const bf16x8*)&W[(size_t)(wn + fn * 16 + ln) * 128 + kf * 32 + q * 8];
        #pragma unroll
        for (int fm = 0; fm < 2; ++fm)
            #pragma unroll
            for (int fn = 0; fn < 4; ++fn)
                acc[fm][fn] = __builtin_amdgcn_mfma_f32_16x16x32_bf16(a[fm], b[fn], acc[fm][fn], 0, 0, 0);
    }
    #pragma unroll
    for (int fm = 0; fm < 2; ++fm)
        #pragma unroll
        for (int r = 0; r < 4; ++r) {
            int rl = wm + fm * 16 + q * 4 + r;
            float s2 = 0.0f;
            #pragma unroll
            for (int fn = 0; fn < 4; ++fn) {
                int col = wn + fn * 16 + ln;
                float vv = acc[fm][fn][r] + bias[col];
                acc[fm][fn][r] = vv;
                s2 += vv * vv;
            }
            #pragma unroll
            for (int off = 1; off < 16; off <<= 1) s2 += __shfl_xor(s2, off, 64);
            if (ln == 0) red[rl][wv & 1] = s2;
        }
    __syncthreads();
    #pragma unroll
    for (int fm = 0; fm < 2; ++fm)
        #pragma unroll
        for (int r = 0; r < 4; ++r) {
            int rl = wm + fm * 16 + q * 4 + r;
            int row = m0 + rl;
            float inv = 1.0f / fmaxf(sqrtf(red[rl][0] + red[rl][1]), 1e-8f);
            #pragma unroll
            for (int fn = 0; fn < 4; ++fn) {
                int col = wn + fn * 16 + ln;
                float vv = acc[fm][fn][r];
                float nv = vv * inv;
                nrm[(size_t)row * 128 + col] = nv;
                if (nb != nullptr) nb[(size_t)row * 128 + col] = f2b(nv);
                raw[(size_t)row * 128 + col] = f2b(vv);
            }
        }
}

// ---------------------------------------------------------------------------
// sim[row] = (1/S) <snb@M_b, tn>_row via MFMA; A/B frags direct from global.
// ---------------------------------------------------------------------------
__global__ __launch_bounds__(256) void simgemm_kernel(
    const unsigned short* __restrict__ snb, const float* __restrict__ tn,
    const unsigned short* __restrict__ Mtb, float* __restrict__ sim)
{
    __shared__ float red[64][2];
    const int tid = threadIdx.x, m0 = blockIdx.x * 64, b = m0 >> 11;
    const int wv = tid >> 6, lane = tid & 63, ln = lane & 15, q = lane >> 4;
    const int wm = (wv >> 1) * 32, wn = (wv & 1) * 64;

    f32x4 acc[2][4] = {};
    #pragma unroll
    for (int kf = 0; kf < 4; ++kf) {
        bf16x8 a[2], bb[4];
        #pragma unroll
        for (int fm = 0; fm < 2; ++fm)
            a[fm] = *(const bf16x8*)&snb[(size_t)(m0 + wm + fm * 16 + ln) * 128 + kf * 32 + q * 8];
        #pragma unroll
        for (int fn = 0; fn < 4; ++fn)
            bb[fn] = *(const bf16x8*)&Mtb[(size_t)b * 16384 + (size_t)(wn + fn * 16 + ln) * 128 + kf * 32 + q * 8];
        #pragma unroll
        for (int fm = 0; fm < 2; ++fm)
            #pragma unroll
            for (int fn = 0; fn < 4; ++fn)
                acc[fm][fn] = __builtin_amdgcn_mfma_f32_16x16x32_bf16(a[fm], bb[fn], acc[fm][fn], 0, 0, 0);
    }
    #pragma unroll
    for (int fm = 0; fm < 2; ++fm)
        #pragma unroll
        for (int r = 0; r < 4; ++r) {
            int rl = wm + fm * 16 + q * 4 + r;
            int row = m0 + rl;
            float s = 0.0f;
            #pragma unroll
            for (int fn = 0; fn < 4; ++fn) {
                int col = wn + fn * 16 + ln;
                s += acc[fm][fn][r] * tn[(size_t)row * 128 + col];
            }
            #pragma unroll
            for (int off = 1; off < 16; off <<= 1) s += __shfl_xor(s, off, 64);
            if (ln == 0) red[rl][wv & 1] = s;
        }
    __syncthreads();
    if (tid < 64) sim[m0 + tid] = (red[tid][0] + red[tid][1]) * (1.0f / (float)SS);
}

// ---------------------------------------------------------------------------
__global__ __launch_bounds__(256) void convertW_kernel(
    const float* __restrict__ w0, const float* __restrict__ w1,
    const float* __restrict__ w2, const float* __restrict__ w3,
    const float* __restrict__ w4, const float* __restrict__ w5,
    const float* __restrict__ w6, const float* __restrict__ w7,
    unsigned short* __restrict__ dst)
{
    int i = blockIdx.x * 256 + threadIdx.x;
    const float* s; int base;
    if      (i < 49152)  { s = w0; base = 0; }
    else if (i < 65536)  { s = w1; base = 49152; }
    else if (i < 131072) { s = w2; base = 65536; }
    else if (i < 196608) { s = w3; base = 131072; }
    else if (i < 212992) { s = w4; base = 196608; }
    else if (i < 229376) { s = w5; base = 212992; }
    else if (i < 278528) { s = w6; base = 229376; }
    else                 { s = w7; base = 278528; }
    dst[i] = f2b(s[i - base]);
}

// ---------------------------------------------------------------------------
// Split-K A^T B per batch (fp32) + transpose-reduce to bf16 (unchanged).
// ---------------------------------------------------------------------------
__global__ __launch_bounds__(256) void atb_split_kernel(
    const float* __restrict__ sn, const float* __restrict__ tn,
    float* __restrict__ part)
{
    const int b = blockIdx.z / ATB_SPLIT;
    const int chunk = blockIdx.z % ATB_SPLIT;
    const int d0 = blockIdx.x * 64, e0 = blockIdx.y * 64;
    __shared__ float Ss[32][68];
    __shared__ float Ts[32][68];
    const int tid = threadIdx.x;
    const int tx = tid % 16, ty = tid / 16;
    const float* sb = sn + (size_t)b * SS * 128;
    const float* tb = tn + (size_t)b * SS * 128;
    const int jbase = chunk * (SS / ATB_SPLIT);
    float acc[4][4] = {};
    for (int j0 = jbase; j0 < jbase + SS / ATB_SPLIT; j0 += 32) {
        #pragma unroll
        for (int it = 0; it < 2; ++it) {
            int idx = tid + it * 256;
            int r = idx / 16, c4 = (idx % 16) * 4;
            *(float4*)&Ss[r][c4] = *(const float4*)&sb[(size_t)(j0 + r) * 128 + d0 + c4];
            *(float4*)&Ts[r][c4] = *(const float4*)&tb[(size_t)(j0 + r) * 128 + e0 + c4];
        }
        __syncthreads();
        #pragma unroll
        for (int kk = 0; kk < 32; ++kk) {
            float4 af = *(const float4*)&Ss[kk][ty * 4];
            float4 wf = *(const float4*)&Ts[kk][tx * 4];
            float a[4] = {af.x, af.y, af.z, af.w};
            float w[4] = {wf.x, wf.y, wf.z, wf.w};
            #pragma unroll
            for (int i = 0; i < 4; ++i)
                #pragma unroll
                for (int j = 0; j < 4; ++j)
                    acc[i][j] = fmaf(a[i], w[j], acc[i][j]);
        }
        __syncthreads();
    }
    float* pp = part + (size_t)(b * ATB_SPLIT + chunk) * 16384;
    #pragma unroll
    for (int i = 0; i < 4; ++i) {
        float4 ov = {acc[i][0], acc[i][1], acc[i][2], acc[i][3]};
        *(float4*)&pp[(size_t)(d0 + ty * 4 + i) * 128 + e0 + tx * 4] = ov;
    }
}

__global__ __launch_bounds__(256) void atb_reduce_kernel(
    const float* __restrict__ part, unsigned short* __restrict__ Mtb)
{
    int i = blockIdx.x * 256 + threadIdx.x;   // 0..131071
    int b = i >> 14, rem = i & 16383;
    int e = rem >> 7, d = rem & 127;
    const float* pp = part + (size_t)b * ATB_SPLIT * 16384 + (size_t)d * 128 + e;
    float s = 0.0f;
    #pragma unroll
    for (int c = 0; c < ATB_SPLIT; ++c) s += pp[(size_t)c * 16384];
    Mtb[i] = f2b(s);
}

// ---------------------------------------------------------------------------
extern "C" void kernel_launch(void* const* d_in, const int* in_sizes, int n_in,
                              void* d_out, int out_size, void* d_ws, size_t ws_size,
                              hipStream_t stream)
{
    const float* x        = (const float*)d_in[0];
    const float* spatial  = (const float*)d_in[1];
    const float* temporal = (const float*)d_in[2];
    const float* lw_in_b  = (const float*)d_in[4];
    const float* lw_out_b = (const float*)d_in[6];
    const float* spat_b   = (const float*)d_in[8];
    const float* temp_b   = (const float*)d_in[10];
    const float* int_in_b = (const float*)d_in[12];
    const float* int_out_b= (const float*)d_in[14];
    const float* ffn_b1   = (const float*)d_in[16];
    const float* ffn_b2   = (const float*)d_in[18];
    const float* ln1_g    = (const float*)d_in[19];
    const float* ln1_b    = (const float*)d_in[20];
    const float* ln2_g    = (const float*)d_in[21];
    const float* ln2_b    = (const float*)d_in[22];
    float* out = (float*)d_out;

    // ---- workspace layout (bytes) ----
    char* base = (char*)d_ws;
    float*          x1   = (float*)(base + 0);            // 8,388,608 (alias part)
    unsigned short* x1b  = (unsigned short*)(base + 8388608);    // 4,194,304
    float*          x2   = (float*)(base + 12582912);     // 8,388,608
    float*          sn   = (float*)(base + 20971520);     // 8,388,608
    float*          tn   = (float*)(base + 29360128);     // 8,388,608
    unsigned short* seb  = (unsigned short*)(base + 37748736);   // 4,194,304
    unsigned short* teb  = (unsigned short*)(base + 41943040);   // 4,194,304
    unsigned short* snb  = (unsigned short*)(base + 46137344);   // 4,194,304
    unsigned short* Mtb  = (unsigned short*)(base + 50331648);   //   262,144
    float*          simb = (float*)(base + 50593792);     //    65,536
    unsigned short* Wb   = (unsigned short*)(base + 50659328);   // 1,179,648
    float*          part = x1;   // x1 dead after ffn_fused; atb runs later

    unsigned short* Wb_lwin  = Wb + 0;
    unsigned short* Wb_lwout = Wb + 49152;
    unsigned short* Wb_ffn1  = Wb + 65536;
    unsigned short* Wb_ffn2  = Wb + 131072;
    unsigned short* Wb_spat  = Wb + 196608;
    unsigned short* Wb_temp  = Wb + 212992;
    unsigned short* Wb_intin = Wb + 229376;
    unsigned short* Wb_intout= Wb + 278528;

    // 1. weight conversion
    convertW_kernel<<<1152, 256, 0, stream>>>(
        (const float*)d_in[3], (const float*)d_in[5], (const float*)d_in[15],
        (const float*)d_in[17], (const float*)d_in[7], (const float*)d_in[9],
        (const float*)d_in[11], (const float*)d_in[13], Wb);
    // 2. fused window block: QKV + causal attn + out-proj + LN1
    win_block<<<256, 256, 0, stream>>>(
        x, Wb_lwin, lw_in_b, Wb_lwout, lw_out_b, ln1_g, ln1_b, x1, x1b);
    // 3. fused FFN + LN2
    ffn_fused<<<256, 256, 0, stream>>>(
        x1b, x1, Wb_ffn1, Wb_ffn2, ffn_b1, ffn_b2, ln2_g, ln2_b, x2);
    // 4. se/te projections + cosine norm
    stproj_kernel<<<dim3(256, 2), 256, 0, stream>>>(
        spatial, temporal, Wb_spat, Wb_temp, spat_b, temp_b,
        sn, tn, snb, seb, teb);
    // 5/6. M_b = sn^T tn (split-K fp32 + transpose-reduce to bf16)
    atb_split_kernel<<<dim3(2, 2, 8 * ATB_SPLIT), 256, 0, stream>>>(sn, tn, part);
    atb_reduce_kernel<<<512, 256, 0, stream>>>(part, Mtb);
    // 7. sim via MFMA
    simgemm_kernel<<<256, 256, 0, stream>>>(snb, tn, Mtb, simb);
    // 8. fused interaction block: intQKV + len-8 MHA + out-proj*sim + x2
    inter_block<<<256, 256, 0, stream>>>(
        seb, teb, Wb_intin, int_in_b, Wb_intout, int_out_b, simb, x2, out);
}

// Round 7
// 241.374 us; speedup vs baseline: 1.0767x; 1.0767x over previous
//
#include <hip/hip_runtime.h>
#include <math.h>

#define BB 8
#define SS 2048
#define NTOK (BB * SS)   // 16384
#define ATB_SPLIT 16

using bf16x8 = __attribute__((ext_vector_type(8))) short;
using f32x4  = __attribute__((ext_vector_type(4))) float;

__device__ __forceinline__ float gelu_exact(float v) {
    return 0.5f * v * (1.0f + erff(v * 0.70710678118654752f));
}
__device__ __forceinline__ unsigned short f2b(float f) {
    unsigned int u = __float_as_uint(f);
    u += 0x7FFFu + ((u >> 16) & 1u);
    return (unsigned short)(u >> 16);
}
__device__ __forceinline__ float b2f(unsigned short u) {
    return __uint_as_float((unsigned int)u << 16);
}
// load 8 fp32 from global, convert -> bf16x8 fragment
__device__ __forceinline__ bf16x8 ldg_f32_b8(const float* p) {
    float4 f0 = *(const float4*)p, f1 = *(const float4*)(p + 4);
    union { ushort4 u[2]; bf16x8 v; } r;
    r.u[0] = (ushort4){f2b(f0.x), f2b(f0.y), f2b(f0.z), f2b(f0.w)};
    r.u[1] = (ushort4){f2b(f1.x), f2b(f1.y), f2b(f1.z), f2b(f1.w)};
    return r.v;
}

// ---------------------------------------------------------------------------
// Fused window block: one block = one 64-token window (grid 256).
//   QKV (3 MFMA passes, W-frags from global bf16) -> MFMA attention
//   (S=QK^T via zero-padded K=32 MFMA, full row softmax, P@V via LDS P) ->
//   out-proj MFMA -> +x residual -> LN1 -> x1 fp32 + x1b bf16.
// ---------------------------------------------------------------------------
__global__ __launch_bounds__(256) void win_block(
    const float* __restrict__ x,
    const unsigned short* __restrict__ Wqkv,  // (384,128) bf16
    const float* __restrict__ b_in,
    const unsigned short* __restrict__ Wout,  // (128,128) bf16
    const float* __restrict__ b_out,
    const float* __restrict__ lng, const float* __restrict__ lnb,
    float* __restrict__ x1, unsigned short* __restrict__ x1b)
{
    __shared__ unsigned short Qs[64 * 136];   // Q; attn-out written in-place
    __shared__ unsigned short Ks[64 * 136];   // K row-major [j][c]
    __shared__ unsigned short Vt[128 * 72];   // V transposed [c][j]
    __shared__ unsigned short Pb[4][32 * 72]; // per-wave P buffer [i_local][j]
    __shared__ float red[2][64][2];
    const int tid = threadIdx.x, m0 = blockIdx.x * 64;
    const int wv = tid >> 6, lane = tid & 63, ln = lane & 15, q = lane >> 4;
    const int wm = (wv >> 1) * 32, wn = (wv & 1) * 64;

    // A-fragments from x fp32, converted once (reused for all 3 passes)
    bf16x8 afr[4][2];
    #pragma unroll
    for (int kf = 0; kf < 4; ++kf)
        #pragma unroll
        for (int fm = 0; fm < 2; ++fm)
            afr[kf][fm] = ldg_f32_b8(x + (size_t)(m0 + wm + fm * 16 + ln) * 128 + kf * 32 + q * 8);

    #pragma unroll
    for (int p = 0; p < 3; ++p) {
        f32x4 acc[2][4] = {};
        #pragma unroll
        for (int kf = 0; kf < 4; ++kf) {
            bf16x8 b[4];
            #pragma unroll
            for (int fn = 0; fn < 4; ++fn)
                b[fn] = *(const bf16x8*)&Wqkv[(size_t)(p * 128 + wn + fn * 16 + ln) * 128 + kf * 32 + q * 8];
            #pragma unroll
            for (int fm = 0; fm < 2; ++fm)
                #pragma unroll
                for (int fn = 0; fn < 4; ++fn)
                    acc[fm][fn] = __builtin_amdgcn_mfma_f32_16x16x32_bf16(afr[kf][fm], b[fn], acc[fm][fn], 0, 0, 0);
        }
        #pragma unroll
        for (int fm = 0; fm < 2; ++fm)
            #pragma unroll
            for (int r = 0; r < 4; ++r) {
                int rl = wm + fm * 16 + q * 4 + r;
                #pragma unroll
                for (int fn = 0; fn < 4; ++fn) {
                    int col = wn + fn * 16 + ln;
                    unsigned short v = f2b(acc[fm][fn][r] + b_in[p * 128 + col]);
                    if (p == 0)      Qs[rl * 136 + col] = v;
                    else if (p == 1) Ks[rl * 136 + col] = v;
                    else             Vt[col * 72 + rl] = v;
                }
            }
    }
    __syncthreads();

    // ---- MFMA attention: wave = (m-half mh, head-quad hq) ----
    {
        const int mh = wv >> 1, hq = wv & 1;
        unsigned short* P = &Pb[wv][0];
        #pragma unroll
        for (int hh = 0; hh < 4; ++hh) {
            const int h = hq * 4 + hh;
            // S = Q K^T  (K dim 16, zero-padded to 32: q>=2 lanes give zeros)
            f32x4 sacc[2][4] = {};
            bf16x8 az[2] = {}, bz[4] = {};
            if (q < 2) {
                #pragma unroll
                for (int fm = 0; fm < 2; ++fm)
                    az[fm] = *(const bf16x8*)&Qs[(mh * 32 + fm * 16 + ln) * 136 + h * 16 + q * 8];
                #pragma unroll
                for (int fn = 0; fn < 4; ++fn)
                    bz[fn] = *(const bf16x8*)&Ks[(fn * 16 + ln) * 136 + h * 16 + q * 8];
            }
            #pragma unroll
            for (int fm = 0; fm < 2; ++fm)
                #pragma unroll
                for (int fn = 0; fn < 4; ++fn)
                    sacc[fm][fn] = __builtin_amdgcn_mfma_f32_16x16x32_bf16(az[fm], bz[fn], sacc[fm][fn], 0, 0, 0);
            // mask + row softmax (C-layout: row = fm*16+q*4+r, col = fn*16+ln)
            float invr[2][4];
            #pragma unroll
            for (int fm = 0; fm < 2; ++fm)
                #pragma unroll
                for (int r = 0; r < 4; ++r) {
                    int gi = mh * 32 + fm * 16 + q * 4 + r;   // query index in window
                    float mx = -1e30f;
                    #pragma unroll
                    for (int fn = 0; fn < 4; ++fn) {
                        int j = fn * 16 + ln;
                        float s = sacc[fm][fn][r] * 0.25f;
                        if (j > gi) s = -1e30f;
                        sacc[fm][fn][r] = s;
                        mx = fmaxf(mx, s);
                    }
                    #pragma unroll
                    for (int off = 1; off < 16; off <<= 1)
                        mx = fmaxf(mx, __shfl_xor(mx, off, 64));
                    float sum = 0.0f;
                    #pragma unroll
                    for (int fn = 0; fn < 4; ++fn) {
                        float p_ = __expf(sacc[fm][fn][r] - mx);
                        sacc[fm][fn][r] = p_;
                        sum += p_;
                    }
                    #pragma unroll
                    for (int off = 1; off < 16; off <<= 1)
                        sum += __shfl_xor(sum, off, 64);
                    invr[fm][r] = 1.0f / sum;
                    #pragma unroll
                    for (int fn = 0; fn < 4; ++fn)
                        P[(fm * 16 + q * 4 + r) * 72 + fn * 16 + ln] = f2b(sacc[fm][fn][r]);
                }
            // O = P V  (K=64, two 32-steps); per-wave P, same-wave LDS order ok
            f32x4 oacc[2] = {};
            #pragma unroll
            for (int kf2 = 0; kf2 < 2; ++kf2) {
                bf16x8 pa[2], vb;
                #pragma unroll
                for (int fm = 0; fm < 2; ++fm)
                    pa[fm] = *(const bf16x8*)&P[(fm * 16 + ln) * 72 + kf2 * 32 + q * 8];
                vb = *(const bf16x8*)&Vt[(h * 16 + ln) * 72 + kf2 * 32 + q * 8];
                #pragma unroll
                for (int fm = 0; fm < 2; ++fm)
                    oacc[fm] = __builtin_amdgcn_mfma_f32_16x16x32_bf16(pa[fm], vb, oacc[fm], 0, 0, 0);
            }
            #pragma unroll
            for (int fm = 0; fm < 2; ++fm)
                #pragma unroll
                for (int r = 0; r < 4; ++r)
                    Qs[(mh * 32 + fm * 16 + q * 4 + r) * 136 + h * 16 + ln] =
                        f2b(oacc[fm][r] * invr[fm][r]);
        }
    }
    __syncthreads();

    // ---- out-proj + residual(x) + LN1 ----
    f32x4 acc[2][4] = {};
    #pragma unroll
    for (int kf = 0; kf < 4; ++kf) {
        bf16x8 a[2], b[4];
        #pragma unroll
        for (int fm = 0; fm < 2; ++fm)
            a[fm] = *(const bf16x8*)&Qs[(wm + fm * 16 + ln) * 136 + kf * 32 + q * 8];
        #pragma unroll
        for (int fn = 0; fn < 4; ++fn)
            b[fn] = *(const bf16x8*)&Wout[(size_t)(wn + fn * 16 + ln) * 128 + kf * 32 + q * 8];
        #pragma unroll
        for (int fm = 0; fm < 2; ++fm)
            #pragma unroll
            for (int fn = 0; fn < 4; ++fn)
                acc[fm][fn] = __builtin_amdgcn_mfma_f32_16x16x32_bf16(a[fm], b[fn], acc[fm][fn], 0, 0, 0);
    }
    #pragma unroll
    for (int fm = 0; fm < 2; ++fm)
        #pragma unroll
        for (int r = 0; r < 4; ++r) {
            int rl = wm + fm * 16 + q * 4 + r;
            int row = m0 + rl;
            float s1 = 0.0f, s2 = 0.0f;
            #pragma unroll
            for (int fn = 0; fn < 4; ++fn) {
                int col = wn + fn * 16 + ln;
                float vv = acc[fm][fn][r] + b_out[col] + x[(size_t)row * 128 + col];
                acc[fm][fn][r] = vv;
                s1 += vv; s2 += vv * vv;
            }
            #pragma unroll
            for (int off = 1; off < 16; off <<= 1) {
                s1 += __shfl_xor(s1, off, 64);
                s2 += __shfl_xor(s2, off, 64);
            }
            if (ln == 0) { red[0][rl][wv & 1] = s1; red[1][rl][wv & 1] = s2; }
        }
    __syncthreads();
    #pragma unroll
    for (int fm = 0; fm < 2; ++fm)
        #pragma unroll
        for (int r = 0; r < 4; ++r) {
            int rl = wm + fm * 16 + q * 4 + r;
            int row = m0 + rl;
            float mu = (red[0][rl][0] + red[0][rl][1]) * (1.0f / 128.0f);
            float var = (red[1][rl][0] + red[1][rl][1]) * (1.0f / 128.0f) - mu * mu;
            float rs = rsqrtf(var + 1e-5f);
            #pragma unroll
            for (int fn = 0; fn < 4; ++fn) {
                int col = wn + fn * 16 + ln;
                float o = (acc[fm][fn][r] - mu) * rs * lng[col] + lnb[col];
                x1[(size_t)row * 128 + col] = o;
                x1b[(size_t)row * 128 + col] = f2b(o);
            }
        }
}

// ---------------------------------------------------------------------------
// Fused interaction block: one block = 8 s-values x all 8 batches (64 rows).
// ---------------------------------------------------------------------------
__global__ __launch_bounds__(256) void inter_block(
    const unsigned short* __restrict__ seb, const unsigned short* __restrict__ teb,
    const unsigned short* __restrict__ Wint,  // (384,128) bf16
    const float* __restrict__ b_int,
    const unsigned short* __restrict__ Wio,   // (128,128) bf16
    const float* __restrict__ b_io,
    const float* __restrict__ sim, const float* __restrict__ x2,
    float* __restrict__ out)
{
    __shared__ unsigned short Qs[64 * 136];
    __shared__ unsigned short KVs[64 * 256];
    const int tid = threadIdx.x, s0 = blockIdx.x * 8;
    const int wv = tid >> 6, lane = tid & 63, ln = lane & 15, q = lane >> 4;
    const int wm = (wv >> 1) * 32, wn = (wv & 1) * 64;

    bf16x8 afr[4][2];
    #pragma unroll
    for (int kf = 0; kf < 4; ++kf)
        #pragma unroll
        for (int fm = 0; fm < 2; ++fm) {
            int rl = wm + fm * 16 + ln;
            size_t g = (size_t)(rl >> 3) * 2048 + s0 + (rl & 7);
            afr[kf][fm] = *(const bf16x8*)&seb[g * 128 + kf * 32 + q * 8];
        }

    #pragma unroll
    for (int p = 0; p < 3; ++p) {
        if (p == 1) {
            #pragma unroll
            for (int kf = 0; kf < 4; ++kf)
                #pragma unroll
                for (int fm = 0; fm < 2; ++fm) {
                    int rl = wm + fm * 16 + ln;
                    size_t g = (size_t)(rl >> 3) * 2048 + s0 + (rl & 7);
                    afr[kf][fm] = *(const bf16x8*)&teb[g * 128 + kf * 32 + q * 8];
                }
        }
        f32x4 acc[2][4] = {};
        #pragma unroll
        for (int kf = 0; kf < 4; ++kf) {
            bf16x8 b[4];
            #pragma unroll
            for (int fn = 0; fn < 4; ++fn)
                b[fn] = *(const bf16x8*)&Wint[(size_t)(p * 128 + wn + fn * 16 + ln) * 128 + kf * 32 + q * 8];
            #pragma unroll
            for (int fm = 0; fm < 2; ++fm)
                #pragma unroll
                for (int fn = 0; fn < 4; ++fn)
                    acc[fm][fn] = __builtin_amdgcn_mfma_f32_16x16x32_bf16(afr[kf][fm], b[fn], acc[fm][fn], 0, 0, 0);
        }
        #pragma unroll
        for (int fm = 0; fm < 2; ++fm)
            #pragma unroll
            for (int r = 0; r < 4; ++r) {
                int rl = wm + fm * 16 + q * 4 + r;
                #pragma unroll
                for (int fn = 0; fn < 4; ++fn) {
                    int col = wn + fn * 16 + ln;
                    unsigned short v = f2b(acc[fm][fn][r] + b_int[p * 128 + col]);
                    if (p == 0) Qs[rl * 136 + col] = v;
                    else        KVs[rl * 256 + (p - 1) * 128 + col] = v;
                }
            }
        __syncthreads();
    }

    // ---- len-8 attention: 512 tasks (ss,h,i), 2 per thread ----
    #pragma unroll
    for (int tt = 0; tt < 2; ++tt) {
        int task = tid + tt * 256;
        int ss = task >> 6, h = (task >> 3) & 7, i = task & 7;
        int rq = i * 8 + ss;
        float qr[16];
        {
            uint4 q0 = *(const uint4*)&Qs[rq * 136 + h * 16];
            uint4 q1 = *(const uint4*)&Qs[rq * 136 + h * 16 + 8];
            const unsigned short* p0 = (const unsigned short*)&q0;
            const unsigned short* p1 = (const unsigned short*)&q1;
            #pragma unroll
            for (int c = 0; c < 8; ++c) { qr[c] = b2f(p0[c]); qr[8 + c] = b2f(p1[c]); }
        }
        float sc[8];
        #pragma unroll
        for (int j = 0; j < 8; ++j) {
            uint4 k0 = *(const uint4*)&KVs[(j * 8 + ss) * 256 + h * 16];
            uint4 k1 = *(const uint4*)&KVs[(j * 8 + ss) * 256 + h * 16 + 8];
            const unsigned short* kp0 = (const unsigned short*)&k0;
            const unsigned short* kp1 = (const unsigned short*)&k1;
            float s = 0.0f;
            #pragma unroll
            for (int c = 0; c < 8; ++c) {
                s = fmaf(qr[c], b2f(kp0[c]), s);
                s = fmaf(qr[8 + c], b2f(kp1[c]), s);
            }
            sc[j] = s * 0.25f;
        }
        float mx = -1e30f;
        #pragma unroll
        for (int j = 0; j < 8; ++j) mx = fmaxf(mx, sc[j]);
        float pe[8], se = 0.0f;
        #pragma unroll
        for (int j = 0; j < 8; ++j) { pe[j] = __expf(sc[j] - mx); se += pe[j]; }
        float inv = 1.0f / se;
        float o[16] = {};
        #pragma unroll
        for (int j = 0; j < 8; ++j) {
            uint4 v0 = *(const uint4*)&KVs[(j * 8 + ss) * 256 + 128 + h * 16];
            uint4 v1 = *(const uint4*)&KVs[(j * 8 + ss) * 256 + 128 + h * 16 + 8];
            const unsigned short* vp0 = (const unsigned short*)&v0;
            const unsigned short* vp1 = (const unsigned short*)&v1;
            #pragma unroll
            for (int c = 0; c < 8; ++c) {
                o[c]     += pe[j] * b2f(vp0[c]);
                o[8 + c] += pe[j] * b2f(vp1[c]);
            }
        }
        ushort4 w0 = (ushort4){f2b(o[0]*inv),  f2b(o[1]*inv),  f2b(o[2]*inv),  f2b(o[3]*inv)};
        ushort4 w1 = (ushort4){f2b(o[4]*inv),  f2b(o[5]*inv),  f2b(o[6]*inv),  f2b(o[7]*inv)};
        ushort4 w2 = (ushort4){f2b(o[8]*inv),  f2b(o[9]*inv),  f2b(o[10]*inv), f2b(o[11]*inv)};
        ushort4 w3 = (ushort4){f2b(o[12]*inv), f2b(o[13]*inv), f2b(o[14]*inv), f2b(o[15]*inv)};
        *(ushort4*)&Qs[rq * 136 + h * 16]      = w0;
        *(ushort4*)&Qs[rq * 136 + h * 16 + 4]  = w1;
        *(ushort4*)&Qs[rq * 136 + h * 16 + 8]  = w2;
        *(ushort4*)&Qs[rq * 136 + h * 16 + 12] = w3;
    }
    __syncthreads();

    // ---- out-proj * sim + x2 ----
    f32x4 acc[2][4] = {};
    #pragma unroll
    for (int kf = 0; kf < 4; ++kf) {
        bf16x8 a[2], b[4];
        #pragma unroll
        for (int fm = 0; fm < 2; ++fm)
            a[fm] = *(const bf16x8*)&Qs[(wm + fm * 16 + ln) * 136 + kf * 32 + q * 8];
        #pragma unroll
        for (int fn = 0; fn < 4; ++fn)
            b[fn] = *(const bf16x8*)&Wio[(size_t)(wn + fn * 16 + ln) * 128 + kf * 32 + q * 8];
        #pragma unroll
        for (int fm = 0; fm < 2; ++fm)
            #pragma unroll
            for (int fn = 0; fn < 4; ++fn)
                acc[fm][fn] = __builtin_amdgcn_mfma_f32_16x16x32_bf16(a[fm], b[fn], acc[fm][fn], 0, 0, 0);
    }
    #pragma unroll
    for (int fm = 0; fm < 2; ++fm)
        #pragma unroll
        for (int r = 0; r < 4; ++r) {
            int rl = wm + fm * 16 + q * 4 + r;
            size_t g = (size_t)(rl >> 3) * 2048 + s0 + (rl & 7);
            float sc = sim[g];
            #pragma unroll
            for (int fn = 0; fn < 4; ++fn) {
                int col = wn + fn * 16 + ln;
                out[g * 128 + col] = (acc[fm][fn][r] + b_io[col]) * sc + x2[g * 128 + col];
            }
        }
}

// ---------------------------------------------------------------------------
// Fused FFN: x2 = LN2( gelu(x1@w1^T+b1) @ w2^T + b2 + x1 ). 64-token blocks,
// grid 256. W-frags direct from global bf16; only Xs + Hs in LDS.
// ---------------------------------------------------------------------------
__global__ __launch_bounds__(256) void ffn_fused(
    const unsigned short* __restrict__ x1b, const float* __restrict__ x1,
    const unsigned short* __restrict__ w1, const unsigned short* __restrict__ w2,
    const float* __restrict__ b1, const float* __restrict__ b2,
    const float* __restrict__ lng, const float* __restrict__ lnb,
    float* __restrict__ x2)
{
    __shared__ unsigned short Xs[64 * 136];
    __shared__ unsigned short Hs[64 * 72];
    __shared__ float red[2][64][2];
    const int tid = threadIdx.x, t0 = blockIdx.x * 64;
    const int wv = tid >> 6, lane = tid & 63, ln = lane & 15, q = lane >> 4;
    const int wm = (wv >> 1) * 32;
    const int wn1 = (wv & 1) * 32, wn2 = (wv & 1) * 64;

    const uint4* X4 = (const uint4*)(x1b + (size_t)t0 * 128);
    #pragma unroll
    for (int t = 0; t < 4; ++t) {
        int idx = tid + t * 256;
        int r = idx >> 4, c = idx & 15;
        *(uint4*)&Xs[r * 136 + c * 8] = X4[r * 16 + c];
    }
    __syncthreads();

    bf16x8 xfr[4][2];
    #pragma unroll
    for (int kf = 0; kf < 4; ++kf)
        #pragma unroll
        for (int fm = 0; fm < 2; ++fm)
            xfr[kf][fm] = *(const bf16x8*)&Xs[(wm + fm * 16 + ln) * 136 + kf * 32 + q * 8];

    f32x4 acc2[2][4] = {};
    for (int ch = 0; ch < 8; ++ch) {
        const int hc0 = ch * 64;
        f32x4 acc1[2][2] = {};
        #pragma unroll
        for (int kf = 0; kf < 4; ++kf) {
            bf16x8 b[2];
            #pragma unroll
            for (int fn = 0; fn < 2; ++fn)
                b[fn] = *(const bf16x8*)&w1[(size_t)(hc0 + wn1 + fn * 16 + ln) * 128 + kf * 32 + q * 8];
            #pragma unroll
            for (int fm = 0; fm < 2; ++fm)
                #pragma unroll
                for (int fn = 0; fn < 2; ++fn)
                    acc1[fm][fn] = __builtin_amdgcn_mfma_f32_16x16x32_bf16(xfr[kf][fm], b[fn], acc1[fm][fn], 0, 0, 0);
        }
        #pragma unroll
        for (int fm = 0; fm < 2; ++fm)
            #pragma unroll
            for (int fn = 0; fn < 2; ++fn)
                #pragma unroll
                for (int r = 0; r < 4; ++r) {
                    int rl = wm + fm * 16 + q * 4 + r;
                    int col = wn1 + fn * 16 + ln;
                    Hs[rl * 72 + col] = f2b(gelu_exact(acc1[fm][fn][r] + b1[hc0 + col]));
                }
        __syncthreads();
        #pragma unroll
        for (int kf = 0; kf < 2; ++kf) {
            bf16x8 a[2], b[4];
            #pragma unroll
            for (int fm = 0; fm < 2; ++fm)
                a[fm] = *(const bf16x8*)&Hs[(wm + fm * 16 + ln) * 72 + kf * 32 + q * 8];
            #pragma unroll
            for (int fn = 0; fn < 4; ++fn)
                b[fn] = *(const bf16x8*)&w2[(size_t)(wn2 + fn * 16 + ln) * 512 + hc0 + kf * 32 + q * 8];
            #pragma unroll
            for (int fm = 0; fm < 2; ++fm)
                #pragma unroll
                for (int fn = 0; fn < 4; ++fn)
                    acc2[fm][fn] = __builtin_amdgcn_mfma_f32_16x16x32_bf16(a[fm], b[fn], acc2[fm][fn], 0, 0, 0);
        }
        __syncthreads();
    }
    #pragma unroll
    for (int fm = 0; fm < 2; ++fm)
        #pragma unroll
        for (int r = 0; r < 4; ++r) {
            int rl = wm + fm * 16 + q * 4 + r;
            int row = t0 + rl;
            float s1 = 0.0f, s2 = 0.0f;
            #pragma unroll
            for (int fn = 0; fn < 4; ++fn) {
                int col = wn2 + fn * 16 + ln;
                float vv = acc2[fm][fn][r] + b2[col] + x1[(size_t)row * 128 + col];
                acc2[fm][fn][r] = vv;
                s1 += vv; s2 += vv * vv;
            }
            #pragma unroll
            for (int off = 1; off < 16; off <<= 1) {
                s1 += __shfl_xor(s1, off, 64);
                s2 += __shfl_xor(s2, off, 64);
            }
            if (ln == 0) { red[0][rl][wv & 1] = s1; red[1][rl][wv & 1] = s2; }
        }
    __syncthreads();
    #pragma unroll
    for (int fm = 0; fm < 2; ++fm)
        #pragma unroll
        for (int r = 0; r < 4; ++r) {
            int rl = wm + fm * 16 + q * 4 + r;
            int row = t0 + rl;
            float mu = (red[0][rl][0] + red[0][rl][1]) * (1.0f / 128.0f);
            float var = (red[1][rl][0] + red[1][rl][1]) * (1.0f / 128.0f) - mu * mu;
            float rs = rsqrtf(var + 1e-5f);
            #pragma unroll
            for (int fn = 0; fn < 4; ++fn) {
                int col = wn2 + fn * 16 + ln;
                x2[(size_t)row * 128 + col] = (acc2[fm][fn][r] - mu) * rs * lng[col] + lnb[col];
            }
        }
}

// ---------------------------------------------------------------------------
// se/te projection + cosine norm, grid (256,2); no LDS staging.
// ---------------------------------------------------------------------------
__global__ __launch_bounds__(256) void stproj_kernel(
    const float* __restrict__ sp, const float* __restrict__ tp,
    const unsigned short* __restrict__ Wsp, const unsigned short* __restrict__ Wtp,
    const float* __restrict__ bsp, const float* __restrict__ btp,
    float* __restrict__ sn, float* __restrict__ tn,
    unsigned short* __restrict__ snb,
    unsigned short* __restrict__ seb, unsigned short* __restrict__ teb)
{
    __shared__ float red[64][2];
    const int tid = threadIdx.x, m0 = blockIdx.x * 64, y = blockIdx.y;
    const float* Af = y ? tp : sp;
    const unsigned short* W = y ? Wtp : Wsp;
    const float* bias = y ? btp : bsp;
    float* nrm = y ? tn : sn;
    unsigned short* nb = y ? nullptr : snb;
    unsigned short* raw = y ? teb : seb;
    const int wv = tid >> 6, lane = tid & 63, ln = lane & 15, q = lane >> 4;
    const int wm = (wv >> 1) * 32, wn = (wv & 1) * 64;

    f32x4 acc[2][4] = {};
    #pragma unroll
    for (int kf = 0; kf < 4; ++kf) {
        bf16x8 a[2], b[4];
        #pragma unroll
        for (int fm = 0; fm < 2; ++fm)
            a[fm] = ldg_f32_b8(Af + (size_t)(m0 + wm + fm * 16 + ln) * 128 + kf * 32 + q * 8);
        #pragma unroll
        for (int fn = 0; fn < 4; ++fn)
            b[fn] = *(const bf16x8*)&W[(size_t)(wn + fn * 16 + ln) * 128 + kf * 32 + q * 8];
        #pragma unroll
        for (int fm = 0; fm < 2; ++fm)
            #pragma unroll
            for (int fn = 0; fn < 4; ++fn)
                acc[fm][fn] = __builtin_amdgcn_mfma_f32_16x16x32_bf16(a[fm], b[fn], acc[fm][fn], 0, 0, 0);
    }
    #pragma unroll
    for (int fm = 0; fm < 2; ++fm)
        #pragma unroll
        for (int r = 0; r < 4; ++r) {
            int rl = wm + fm * 16 + q * 4 + r;
            float s2 = 0.0f;
            #pragma unroll
            for (int fn = 0; fn < 4; ++fn) {
                int col = wn + fn * 16 + ln;
                float vv = acc[fm][fn][r] + bias[col];
                acc[fm][fn][r] = vv;
                s2 += vv * vv;
            }
            #pragma unroll
            for (int off = 1; off < 16; off <<= 1) s2 += __shfl_xor(s2, off, 64);
            if (ln == 0) red[rl][wv & 1] = s2;
        }
    __syncthreads();
    #pragma unroll
    for (int fm = 0; fm < 2; ++fm)
        #pragma unroll
        for (int r = 0; r < 4; ++r) {
            int rl = wm + fm * 16 + q * 4 + r;
            int row = m0 + rl;
            float inv = 1.0f / fmaxf(sqrtf(red[rl][0] + red[rl][1]), 1e-8f);
            #pragma unroll
            for (int fn = 0; fn < 4; ++fn) {
                int col = wn + fn * 16 + ln;
                float vv = acc[fm][fn][r];
                float nv = vv * inv;
                nrm[(size_t)row * 128 + col] = nv;
                if (nb != nullptr) nb[(size_t)row * 128 + col] = f2b(nv);
                raw[(size_t)row * 128 + col] = f2b(vv);
            }
        }
}

// ---------------------------------------------------------------------------
// sim[row] = (1/S) <snb@M_b, tn>_row via MFMA; frags direct from global.
// ---------------------------------------------------------------------------
__global__ __launch_bounds__(256) void simgemm_kernel(
    const unsigned short* __restrict__ snb, const float* __restrict__ tn,
    const unsigned short* __restrict__ Mtb, float* __restrict__ sim)
{
    __shared__ float red[64][2];
    const int tid = threadIdx.x, m0 = blockIdx.x * 64, b = m0 >> 11;
    const int wv = tid >> 6, lane = tid & 63, ln = lane & 15, q = lane >> 4;
    const int wm = (wv >> 1) * 32, wn = (wv & 1) * 64;

    f32x4 acc[2][4] = {};
    #pragma unroll
    for (int kf = 0; kf < 4; ++kf) {
        bf16x8 a[2], bb[4];
        #pragma unroll
        for (int fm = 0; fm < 2; ++fm)
            a[fm] = *(const bf16x8*)&snb[(size_t)(m0 + wm + fm * 16 + ln) * 128 + kf * 32 + q * 8];
        #pragma unroll
        for (int fn = 0; fn < 4; ++fn)
            bb[fn] = *(const bf16x8*)&Mtb[(size_t)b * 16384 + (size_t)(wn + fn * 16 + ln) * 128 + kf * 32 + q * 8];
        #pragma unroll
        for (int fm = 0; fm < 2; ++fm)
            #pragma unroll
            for (int fn = 0; fn < 4; ++fn)
                acc[fm][fn] = __builtin_amdgcn_mfma_f32_16x16x32_bf16(a[fm], bb[fn], acc[fm][fn], 0, 0, 0);
    }
    #pragma unroll
    for (int fm = 0; fm < 2; ++fm)
        #pragma unroll
        for (int r = 0; r < 4; ++r) {
            int rl = wm + fm * 16 + q * 4 + r;
            int row = m0 + rl;
            float s = 0.0f;
            #pragma unroll
            for (int fn = 0; fn < 4; ++fn) {
                int col = wn + fn * 16 + ln;
                s += acc[fm][fn][r] * tn[(size_t)row * 128 + col];
            }
            #pragma unroll
            for (int off = 1; off < 16; off <<= 1) s += __shfl_xor(s, off, 64);
            if (ln == 0) red[rl][wv & 1] = s;
        }
    __syncthreads();
    if (tid < 64) sim[m0 + tid] = (red[tid][0] + red[tid][1]) * (1.0f / (float)SS);
}

// ---------------------------------------------------------------------------
__global__ __launch_bounds__(256) void convertW_kernel(
    const float* __restrict__ w0, const float* __restrict__ w1,
    const float* __restrict__ w2, const float* __restrict__ w3,
    const float* __restrict__ w4, const float* __restrict__ w5,
    const float* __restrict__ w6, const float* __restrict__ w7,
    unsigned short* __restrict__ dst)
{
    int i = blockIdx.x * 256 + threadIdx.x;
    const float* s; int base;
    if      (i < 49152)  { s = w0; base = 0; }
    else if (i < 65536)  { s = w1; base = 49152; }
    else if (i < 131072) { s = w2; base = 65536; }
    else if (i < 196608) { s = w3; base = 131072; }
    else if (i < 212992) { s = w4; base = 196608; }
    else if (i < 229376) { s = w5; base = 212992; }
    else if (i < 278528) { s = w6; base = 229376; }
    else                 { s = w7; base = 278528; }
    dst[i] = f2b(s[i - base]);
}

// ---------------------------------------------------------------------------
// Split-K A^T B per batch (fp32) + transpose-reduce to bf16.
// ---------------------------------------------------------------------------
__global__ __launch_bounds__(256) void atb_split_kernel(
    const float* __restrict__ sn, const float* __restrict__ tn,
    float* __restrict__ part)
{
    const int b = blockIdx.z / ATB_SPLIT;
    const int chunk = blockIdx.z % ATB_SPLIT;
    const int d0 = blockIdx.x * 64, e0 = blockIdx.y * 64;
    __shared__ float Ss[32][68];
    __shared__ float Ts[32][68];
    const int tid = threadIdx.x;
    const int tx = tid % 16, ty = tid / 16;
    const float* sb = sn + (size_t)b * SS * 128;
    const float* tb = tn + (size_t)b * SS * 128;
    const int jbase = chunk * (SS / ATB_SPLIT);
    float acc[4][4] = {};
    for (int j0 = jbase; j0 < jbase + SS / ATB_SPLIT; j0 += 32) {
        #pragma unroll
        for (int it = 0; it < 2; ++it) {
            int idx = tid + it * 256;
            int r = idx / 16, c4 = (idx % 16) * 4;
            *(float4*)&Ss[r][c4] = *(const float4*)&sb[(size_t)(j0 + r) * 128 + d0 + c4];
            *(float4*)&Ts[r][c4] = *(const float4*)&tb[(size_t)(j0 + r) * 128 + e0 + c4];
        }
        __syncthreads();
        #pragma unroll
        for (int kk = 0; kk < 32; ++kk) {
            float4 af = *(const float4*)&Ss[kk][ty * 4];
            float4 wf = *(const float4*)&Ts[kk][tx * 4];
            float a[4] = {af.x, af.y, af.z, af.w};
            float w[4] = {wf.x, wf.y, wf.z, wf.w};
            #pragma unroll
            for (int i = 0; i < 4; ++i)
                #pragma unroll
                for (int j = 0; j < 4; ++j)
                    acc[i][j] = fmaf(a[i], w[j], acc[i][j]);
        }
        __syncthreads();
    }
    float* pp = part + (size_t)(b * ATB_SPLIT + chunk) * 16384;
    #pragma unroll
    for (int i = 0; i < 4; ++i) {
        float4 ov = {acc[i][0], acc[i][1], acc[i][2], acc[i][3]};
        *(float4*)&pp[(size_t)(d0 + ty * 4 + i) * 128 + e0 + tx * 4] = ov;
    }
}

__global__ __launch_bounds__(256) void atb_reduce_kernel(
    const float* __restrict__ part, unsigned short* __restrict__ Mtb)
{
    int i = blockIdx.x * 256 + threadIdx.x;   // 0..131071
    int b = i >> 14, rem = i & 16383;
    int e = rem >> 7, d = rem & 127;
    const float* pp = part + (size_t)b * ATB_SPLIT * 16384 + (size_t)d * 128 + e;
    float s = 0.0f;
    #pragma unroll
    for (int c = 0; c < ATB_SPLIT; ++c) s += pp[(size_t)c * 16384];
    Mtb[i] = f2b(s);
}

// ---------------------------------------------------------------------------
extern "C" void kernel_launch(void* const* d_in, const int* in_sizes, int n_in,
                              void* d_out, int out_size, void* d_ws, size_t ws_size,
                              hipStream_t stream)
{
    const float* x        = (const float*)d_in[0];
    const float* spatial  = (const float*)d_in[1];
    const float* temporal = (const float*)d_in[2];
    const float* lw_in_b  = (const float*)d_in[4];
    const float* lw_out_b = (const float*)d_in[6];
    const float* spat_b   = (const float*)d_in[8];
    const float* temp_b   = (const float*)d_in[10];
    const float* int_in_b = (const float*)d_in[12];
    const float* int_out_b= (const float*)d_in[14];
    const float* ffn_b1   = (const float*)d_in[16];
    const float* ffn_b2   = (const float*)d_in[18];
    const float* ln1_g    = (const float*)d_in[19];
    const float* ln1_b    = (const float*)d_in[20];
    const float* ln2_g    = (const float*)d_in[21];
    const float* ln2_b    = (const float*)d_in[22];
    float* out = (float*)d_out;

    // ---- workspace layout (bytes) ----
    char* base = (char*)d_ws;
    float*          x1   = (float*)(base + 0);            // 8,388,608 (alias part)
    unsigned short* x1b  = (unsigned short*)(base + 8388608);    // 4,194,304
    float*          x2   = (float*)(base + 12582912);     // 8,388,608
    float*          sn   = (float*)(base + 20971520);     // 8,388,608
    float*          tn   = (float*)(base + 29360128);     // 8,388,608
    unsigned short* seb  = (unsigned short*)(base + 37748736);   // 4,194,304
    unsigned short* teb  = (unsigned short*)(base + 41943040);   // 4,194,304
    unsigned short* snb  = (unsigned short*)(base + 46137344);   // 4,194,304
    unsigned short* Mtb  = (unsigned short*)(base + 50331648);   //   262,144
    float*          simb = (float*)(base + 50593792);     //    65,536
    unsigned short* Wb   = (unsigned short*)(base + 50659328);   // 1,179,648
    float*          part = x1;   // x1 dead after ffn_fused; atb runs later

    unsigned short* Wb_lwin  = Wb + 0;
    unsigned short* Wb_lwout = Wb + 49152;
    unsigned short* Wb_ffn1  = Wb + 65536;
    unsigned short* Wb_ffn2  = Wb + 131072;
    unsigned short* Wb_spat  = Wb + 196608;
    unsigned short* Wb_temp  = Wb + 212992;
    unsigned short* Wb_intin = Wb + 229376;
    unsigned short* Wb_intout= Wb + 278528;

    // 1. weight conversion
    convertW_kernel<<<1152, 256, 0, stream>>>(
        (const float*)d_in[3], (const float*)d_in[5], (const float*)d_in[15],
        (const float*)d_in[17], (const float*)d_in[7], (const float*)d_in[9],
        (const float*)d_in[11], (const float*)d_in[13], Wb);
    // 2. fused window block: QKV + MFMA causal attn + out-proj + LN1
    win_block<<<256, 256, 0, stream>>>(
        x, Wb_lwin, lw_in_b, Wb_lwout, lw_out_b, ln1_g, ln1_b, x1, x1b);
    // 3. fused FFN + LN2
    ffn_fused<<<256, 256, 0, stream>>>(
        x1b, x1, Wb_ffn1, Wb_ffn2, ffn_b1, ffn_b2, ln2_g, ln2_b, x2);
    // 4. se/te projections + cosine norm
    stproj_kernel<<<dim3(256, 2), 256, 0, stream>>>(
        spatial, temporal, Wb_spat, Wb_temp, spat_b, temp_b,
        sn, tn, snb, seb, teb);
    // 5/6. M_b = sn^T tn (split-K fp32 + transpose-reduce to bf16)
    atb_split_kernel<<<dim3(2, 2, 8 * ATB_SPLIT), 256, 0, stream>>>(sn, tn, part);
    atb_reduce_kernel<<<512, 256, 0, stream>>>(part, Mtb);
    // 7. sim via MFMA
    simgemm_kernel<<<256, 256, 0, stream>>>(snb, tn, Mtb, simb);
    // 8. fused interaction block: intQKV + len-8 MHA + out-proj*sim + x2
    inter_block<<<256, 256, 0, stream>>>(
        seb, teb, Wb_intin, int_in_b, Wb_intout, int_out_b, simb, x2, out);
}